// Round 7
// baseline (88.886 us; speedup 1.0000x reference)
//
#include <hip/hip_runtime.h>

constexpr int BB = 16;     // batch
constexpr int CC = 512;    // channels
constexpr int PP = 32;     // clusters
constexpr int NN = 4096;   // H*W
constexpr int TN = 128;    // assign n-tile per block

using f32x4 = __attribute__((ext_vector_type(4))) float;
using bf16x8 = __attribute__((ext_vector_type(8))) short;
typedef unsigned int uint;

__device__ __forceinline__ ushort f2bf(float f) {
  unsigned u = __builtin_bit_cast(unsigned, f);
  u += 0x7FFFu + ((u >> 16) & 1u);   // round-to-nearest-even
  return (ushort)(u >> 16);
}

// pack float -> (bf16_lo << 16) | bf16_hi, where hi = bf16(f), lo = bf16(f - hi)
__device__ __forceinline__ uint packbf(float f) {
  uint u = __builtin_bit_cast(uint, f);
  uint hi = (u + (0x7FFFu + ((u >> 16) & 1u))) >> 16;
  float hif = __builtin_bit_cast(float, hi << 16);
  float lof = f - hif;
  uint ul = __builtin_bit_cast(uint, lof);
  uint lo = (ul + (0x7FFFu + ((ul >> 16) & 1u))) >> 16;
  return (lo << 16) | hi;
}

struct BfPair { bf16x8 hi, lo; };

// unpack 8 packed uints (row + co .. co+7) into hi/lo bf16x8 fragments
__device__ __forceinline__ BfPair unpack8(const uint* __restrict__ row, int co) {
  uint4 a = *(const uint4*)(row + co);
  uint4 b = *(const uint4*)(row + co + 4);
  union { bf16x8 v; uint d[4]; } H, L;
  H.d[0] = (a.x & 0xffffu) | (a.y << 16); L.d[0] = (a.x >> 16) | (a.y & 0xffff0000u);
  H.d[1] = (a.z & 0xffffu) | (a.w << 16); L.d[1] = (a.z >> 16) | (a.w & 0xffff0000u);
  H.d[2] = (b.x & 0xffffu) | (b.y << 16); L.d[2] = (b.x >> 16) | (b.y & 0xffff0000u);
  H.d[3] = (b.z & 0xffffu) | (b.w << 16); L.d[3] = (b.z >> 16) | (b.w & 0xffff0000u);
  return {H.v, L.v};
}

// ---------------------------------------------------------------------------
// prep: beta = sigmoid(sf), rbeta = 1/beta, csq[p] = |centers_p|^2 (fp32).
// Also zeroes sum_ass.
// ---------------------------------------------------------------------------
__global__ __launch_bounds__(64) void prep_kernel(
    const float* __restrict__ w, const float* __restrict__ sf,
    float* __restrict__ beta, float* __restrict__ rbeta,
    float* __restrict__ csq, float* __restrict__ sum_ass) {
  int p = blockIdx.x;
  int t = threadIdx.x;
  if (t < 16) sum_ass[p * 16 + t] = 0.f;
  float s = 0.f;
  for (int i = t; i < CC; i += 64) {
    float v = w[p * CC + i];
    s = fmaf(v, v, s);
  }
#pragma unroll
  for (int off = 32; off; off >>= 1) s += __shfl_down(s, off);
  if (t == 0) {
    csq[p] = s;
    float e = __expf(-sf[p]);
    rbeta[p] = 1.f + e;            // 1/beta
    beta[p] = 1.f / (1.f + e);     // beta
  }
}

// ---------------------------------------------------------------------------
// assign via split-bf16 MFMA: cx[p][n] = sum_c cent[p][c]*x[c][n], computed as
// hi*hi + hi*lo + lo*hi (3 MFMAs, fp32 accumulate) for ~fp32 accuracy.
// grid 512 (16 b x 32 n-tiles of 128), block 256 = 4 waves.
// Wave wv owns n in [32wv,32wv+32) (2 n-frags), all 32 p (2 p-frags).
// x transposed+packed into LDS [n][c] uint; centers packed [p][c] uint.
// xsq in fp32 from staging regs (shuffle-reduced); softmax in-register via
// shfl_xor(16/32); fused sum_ass via shfl_xor(1..8)+atomics.
// ---------------------------------------------------------------------------
__global__ __launch_bounds__(256, 3) void assign_kernel(
    const float* __restrict__ x, const float* __restrict__ w,
    const float* __restrict__ rbeta, const float* __restrict__ csq,
    float* __restrict__ assign_out, float* __restrict__ sum_ass) {
  __shared__ uint xpk[128][68];       // [n][c-chunk 64 + pad] packed, 34.8 KB
  __shared__ uint cpk[32][68];        // [p][c-chunk 64 + pad] packed, 8.7 KB
  __shared__ float xsqw[4][4][32];    // per-wave xsq partials, 2 KB
  __shared__ float xsqf[128];         // final xsq per n, 0.5 KB

  int tid = threadIdx.x;
  int wv = tid >> 6, lane = tid & 63;
  int l15 = lane & 15, lg = lane >> 4;
  int b = blockIdx.x >> 5;
  int n0 = (blockIdx.x & 31) * TN;

  int c_s = tid >> 2;          // staging c row 0..63 (within chunk)
  int q = tid & 3;             // staging n window (32 n)
  int p_s = tid >> 3;          // centers staging p 0..31
  int cq8 = (tid & 7) << 3;    // centers staging c offset 0..56

  const float* xb = x + (size_t)b * CC * NN + n0 + q * 32;
  const float* wb = w + (size_t)p_s * CC + cq8;

  f32x4 acc[2][2];
#pragma unroll
  for (int i = 0; i < 2; ++i)
#pragma unroll
    for (int j = 0; j < 2; ++j) acc[i][j] = {0.f, 0.f, 0.f, 0.f};
  float sq[32];
#pragma unroll
  for (int i = 0; i < 32; ++i) sq[i] = 0.f;

  float4 xr[8], wr0, wr1;
  // ---- prologue: load + stage chunk 0
#pragma unroll
  for (int i = 0; i < 8; ++i)
    xr[i] = *(const float4*)&xb[(size_t)c_s * NN + i * 4];
  wr0 = *(const float4*)&wb[0];
  wr1 = *(const float4*)&wb[4];
#pragma unroll
  for (int i = 0; i < 8; ++i) {
    float4 v = xr[i];
    sq[4 * i + 0] = fmaf(v.x, v.x, sq[4 * i + 0]);
    sq[4 * i + 1] = fmaf(v.y, v.y, sq[4 * i + 1]);
    sq[4 * i + 2] = fmaf(v.z, v.z, sq[4 * i + 2]);
    sq[4 * i + 3] = fmaf(v.w, v.w, sq[4 * i + 3]);
    int nr = q * 32 + i * 4;
    xpk[nr + 0][c_s] = packbf(v.x);
    xpk[nr + 1][c_s] = packbf(v.y);
    xpk[nr + 2][c_s] = packbf(v.z);
    xpk[nr + 3][c_s] = packbf(v.w);
  }
  {
    uint4 u0 = {packbf(wr0.x), packbf(wr0.y), packbf(wr0.z), packbf(wr0.w)};
    uint4 u1 = {packbf(wr1.x), packbf(wr1.y), packbf(wr1.z), packbf(wr1.w)};
    *(uint4*)&cpk[p_s][cq8] = u0;
    *(uint4*)&cpk[p_s][cq8 + 4] = u1;
  }
  __syncthreads();

  // ---- main loop over c-chunks of 64
  for (int c0 = 0; c0 < CC; c0 += 64) {
    bool more = (c0 + 64 < CC);
    if (more) {   // prefetch next chunk into regs
#pragma unroll
      for (int i = 0; i < 8; ++i)
        xr[i] = *(const float4*)&xb[(size_t)(c0 + 64 + c_s) * NN + i * 4];
      wr0 = *(const float4*)&wb[c0 + 64];
      wr1 = *(const float4*)&wb[c0 + 64 + 4];
    }
#pragma unroll
    for (int ks = 0; ks < 2; ++ks) {
      int co = ks * 32 + lg * 8;
      BfPair A0 = unpack8(&cpk[l15][0], co);
      BfPair A1 = unpack8(&cpk[l15 + 16][0], co);
      BfPair B0 = unpack8(&xpk[wv * 32 + l15][0], co);
      BfPair B1 = unpack8(&xpk[wv * 32 + 16 + l15][0], co);
      acc[0][0] = __builtin_amdgcn_mfma_f32_16x16x32_bf16(A0.hi, B0.hi, acc[0][0], 0, 0, 0);
      acc[0][1] = __builtin_amdgcn_mfma_f32_16x16x32_bf16(A0.hi, B1.hi, acc[0][1], 0, 0, 0);
      acc[1][0] = __builtin_amdgcn_mfma_f32_16x16x32_bf16(A1.hi, B0.hi, acc[1][0], 0, 0, 0);
      acc[1][1] = __builtin_amdgcn_mfma_f32_16x16x32_bf16(A1.hi, B1.hi, acc[1][1], 0, 0, 0);
      acc[0][0] = __builtin_amdgcn_mfma_f32_16x16x32_bf16(A0.hi, B0.lo, acc[0][0], 0, 0, 0);
      acc[0][1] = __builtin_amdgcn_mfma_f32_16x16x32_bf16(A0.hi, B1.lo, acc[0][1], 0, 0, 0);
      acc[1][0] = __builtin_amdgcn_mfma_f32_16x16x32_bf16(A1.hi, B0.lo, acc[1][0], 0, 0, 0);
      acc[1][1] = __builtin_amdgcn_mfma_f32_16x16x32_bf16(A1.hi, B1.lo, acc[1][1], 0, 0, 0);
      acc[0][0] = __builtin_amdgcn_mfma_f32_16x16x32_bf16(A0.lo, B0.hi, acc[0][0], 0, 0, 0);
      acc[0][1] = __builtin_amdgcn_mfma_f32_16x16x32_bf16(A0.lo, B1.hi, acc[0][1], 0, 0, 0);
      acc[1][0] = __builtin_amdgcn_mfma_f32_16x16x32_bf16(A1.lo, B0.hi, acc[1][0], 0, 0, 0);
      acc[1][1] = __builtin_amdgcn_mfma_f32_16x16x32_bf16(A1.lo, B1.hi, acc[1][1], 0, 0, 0);
    }
    if (more) {
      __syncthreads();   // all waves done reading old chunk
#pragma unroll
      for (int i = 0; i < 8; ++i) {
        float4 v = xr[i];
        sq[4 * i + 0] = fmaf(v.x, v.x, sq[4 * i + 0]);
        sq[4 * i + 1] = fmaf(v.y, v.y, sq[4 * i + 1]);
        sq[4 * i + 2] = fmaf(v.z, v.z, sq[4 * i + 2]);
        sq[4 * i + 3] = fmaf(v.w, v.w, sq[4 * i + 3]);
        int nr = q * 32 + i * 4;
        xpk[nr + 0][c_s] = packbf(v.x);
        xpk[nr + 1][c_s] = packbf(v.y);
        xpk[nr + 2][c_s] = packbf(v.z);
        xpk[nr + 3][c_s] = packbf(v.w);
      }
      uint4 u0 = {packbf(wr0.x), packbf(wr0.y), packbf(wr0.z), packbf(wr0.w)};
      uint4 u1 = {packbf(wr1.x), packbf(wr1.y), packbf(wr1.z), packbf(wr1.w)};
      *(uint4*)&cpk[p_s][cq8] = u0;
      *(uint4*)&cpk[p_s][cq8 + 4] = u1;
      __syncthreads();
    }
  }

  // ---- xsq reduce: sum over c_s within wave (lane bits 2..5), then x-wave
#pragma unroll
  for (int i = 0; i < 32; ++i) {
    sq[i] += __shfl_xor(sq[i], 4);
    sq[i] += __shfl_xor(sq[i], 8);
    sq[i] += __shfl_xor(sq[i], 16);
    sq[i] += __shfl_xor(sq[i], 32);
  }
  if ((lane >> 2) == 0) {
#pragma unroll
    for (int i = 0; i < 32; ++i) xsqw[wv][lane & 3][i] = sq[i];
  }
  __syncthreads();
  if (tid < 128)
    xsqf[tid] = xsqw[0][tid >> 5][tid & 31] + xsqw[1][tid >> 5][tid & 31] +
                xsqw[2][tid >> 5][tid & 31] + xsqw[3][tid >> 5][tid & 31];
  __syncthreads();

  float xsqn0 = xsqf[wv * 32 + l15];
  float xsqn1 = xsqf[wv * 32 + 16 + l15];

  // per-lane p constants: p = pf*16 + lg*4 + i
  float csqv[2][4], rbv[2][4];
#pragma unroll
  for (int pf = 0; pf < 2; ++pf)
#pragma unroll
    for (int i = 0; i < 4; ++i) {
      int p = pf * 16 + lg * 4 + i;
      csqv[pf][i] = csq[p];
      rbv[pf][i] = rbeta[p];
    }

  // logits + in-register softmax over p (shfl_xor 16/32 spans the lg groups)
  float L[2][2][4];
  float m0 = -3.4e38f, m1 = -3.4e38f;
#pragma unroll
  for (int pf = 0; pf < 2; ++pf)
#pragma unroll
    for (int i = 0; i < 4; ++i) {
      float l0 = fminf(2.f * acc[pf][0][i] - xsqn0 - csqv[pf][i], 0.f) * rbv[pf][i];
      float l1 = fminf(2.f * acc[pf][1][i] - xsqn1 - csqv[pf][i], 0.f) * rbv[pf][i];
      L[pf][0][i] = l0; L[pf][1][i] = l1;
      m0 = fmaxf(m0, l0); m1 = fmaxf(m1, l1);
    }
  m0 = fmaxf(m0, __shfl_xor(m0, 16)); m0 = fmaxf(m0, __shfl_xor(m0, 32));
  m1 = fmaxf(m1, __shfl_xor(m1, 16)); m1 = fmaxf(m1, __shfl_xor(m1, 32));
  float s0 = 0.f, s1 = 0.f;
#pragma unroll
  for (int pf = 0; pf < 2; ++pf)
#pragma unroll
    for (int i = 0; i < 4; ++i) {
      float e0 = __expf(L[pf][0][i] - m0);
      float e1 = __expf(L[pf][1][i] - m1);
      L[pf][0][i] = e0; L[pf][1][i] = e1;
      s0 += e0; s1 += e1;
    }
  s0 += __shfl_xor(s0, 16); s0 += __shfl_xor(s0, 32);
  s1 += __shfl_xor(s1, 16); s1 += __shfl_xor(s1, 32);
  float inv0 = 1.f / s0, inv1 = 1.f / s1;

  // store assign + fused sum_ass
  float* aoB = assign_out + (size_t)b * PP * NN + n0 + wv * 32 + l15;
  float sa[2][4];
#pragma unroll
  for (int pf = 0; pf < 2; ++pf)
#pragma unroll
    for (int i = 0; i < 4; ++i) {
      int p = pf * 16 + lg * 4 + i;
      float a0 = L[pf][0][i] * inv0;
      float a1 = L[pf][1][i] * inv1;
      aoB[(size_t)p * NN] = a0;
      aoB[(size_t)p * NN + 16] = a1;
      sa[pf][i] = a0 + a1;
    }
#pragma unroll
  for (int pf = 0; pf < 2; ++pf)
#pragma unroll
    for (int i = 0; i < 4; ++i) {
      float v = sa[pf][i];
      v += __shfl_xor(v, 1); v += __shfl_xor(v, 2);
      v += __shfl_xor(v, 4); v += __shfl_xor(v, 8);
      if (l15 == 0) atomicAdd(&sum_ass[b * PP + pf * 16 + lg * 4 + i], v);
    }
}

// ---------------------------------------------------------------------------
// qx via bf16 MFMA (unchanged from R6, passing):
// qx_part[kc][b][p][c] = sum_{n in chunk} a[p][n]*x[c][n].
// ---------------------------------------------------------------------------
__global__ __launch_bounds__(256) void qx_kernel(
    const float* __restrict__ x, const float* __restrict__ assign,
    float* __restrict__ qx_part) {
  __shared__ ushort xbf[128][136];  // [c_local][n_local] bf16, 34.8 KB
  __shared__ ushort abf[32][136];   // [p][n_local] bf16, 8.7 KB

  int tid = threadIdx.x;
  int b = blockIdx.y;
  int kc = blockIdx.x >> 2;   // 0..7: k-chunk of 512 n
  int ct = blockIdx.x & 3;    // 0..3: c-tile of 128
  int wv = tid >> 6, lane = tid & 63;
  int l15 = lane & 15, lg = lane >> 4;

  const float* xb = x + ((size_t)b * CC + ct * 128) * NN + kc * 512;
  const float* ab = assign + (size_t)b * PP * NN + kc * 512;

  int c_s = tid >> 1;            // x staging row 0..127
  int nh  = (tid & 1) << 6;      // n half: 0 or 64
  int p_s = tid >> 3;            // a staging p 0..31
  int na  = (tid & 7) << 4;      // a staging n off 0..112

  f32x4 acc[2][2];
#pragma unroll
  for (int i = 0; i < 2; ++i)
#pragma unroll
    for (int j = 0; j < 2; ++j) acc[i][j] = {0.f, 0.f, 0.f, 0.f};

  for (int ch = 0; ch < 4; ++ch) {   // 4 inner chunks of 128 n
    int nb = ch * 128;
    if (ch) __syncthreads();
#pragma unroll
    for (int h = 0; h < 2; ++h) {
      float4 v[8];
#pragma unroll
      for (int i = 0; i < 8; ++i)
        v[i] = *(const float4*)&xb[(size_t)c_s * NN + nb + nh + h * 32 + i * 4];
#pragma unroll
      for (int i = 0; i < 8; ++i) {
        ushort4 u;
        u.x = f2bf(v[i].x); u.y = f2bf(v[i].y);
        u.z = f2bf(v[i].z); u.w = f2bf(v[i].w);
        *(ushort4*)&xbf[c_s][nh + h * 32 + i * 4] = u;
      }
    }
    {
      float4 v[4];
#pragma unroll
      for (int i = 0; i < 4; ++i)
        v[i] = *(const float4*)&ab[(size_t)p_s * NN + nb + na + i * 4];
#pragma unroll
      for (int i = 0; i < 4; ++i) {
        ushort4 u;
        u.x = f2bf(v[i].x); u.y = f2bf(v[i].y);
        u.z = f2bf(v[i].z); u.w = f2bf(v[i].w);
        *(ushort4*)&abf[p_s][na + i * 4] = u;
      }
    }
    __syncthreads();
#pragma unroll
    for (int ks = 0; ks < 4; ++ks) {
      int nf = ks * 32 + lg * 8;
      bf16x8 a0 = *(const bf16x8*)&abf[l15][nf];
      bf16x8 a1 = *(const bf16x8*)&abf[16 + l15][nf];
      bf16x8 b0 = *(const bf16x8*)&xbf[wv * 32 + l15][nf];
      bf16x8 b1 = *(const bf16x8*)&xbf[wv * 32 + 16 + l15][nf];
      acc[0][0] = __builtin_amdgcn_mfma_f32_16x16x32_bf16(a0, b0, acc[0][0], 0, 0, 0);
      acc[0][1] = __builtin_amdgcn_mfma_f32_16x16x32_bf16(a0, b1, acc[0][1], 0, 0, 0);
      acc[1][0] = __builtin_amdgcn_mfma_f32_16x16x32_bf16(a1, b0, acc[1][0], 0, 0, 0);
      acc[1][1] = __builtin_amdgcn_mfma_f32_16x16x32_bf16(a1, b1, acc[1][1], 0, 0, 0);
    }
  }

#pragma unroll
  for (int pf = 0; pf < 2; ++pf)
#pragma unroll
    for (int cf = 0; cf < 2; ++cf)
#pragma unroll
      for (int i = 0; i < 4; ++i) {
        int p = pf * 16 + lg * 4 + i;
        int c = ct * 128 + wv * 32 + cf * 16 + l15;
        qx_part[(((size_t)kc * BB + b) * PP + p) * CC + c] = acc[pf][cf][i];
      }
}

// ---------------------------------------------------------------------------
// finalize (unchanged from R5/R6)
// ---------------------------------------------------------------------------
__global__ __launch_bounds__(256) void finalize_kernel(
    const float* __restrict__ qx_part, const float* __restrict__ w,
    const float* __restrict__ beta, const float* __restrict__ sum_ass,
    float* __restrict__ out_t) {
  int b = blockIdx.x >> 5;
  int p = blockIdx.x & 31;
  int tid = threadIdx.x;
  int wave = tid >> 6, lane = tid & 63;

  float inv_sa = 1.f / fmaxf(sum_ass[b * PP + p], 1e-5f);
  float rsig = rsqrtf(0.5f * beta[p]);

  int c0 = tid, c1 = tid + 256;
  float q0 = 0.f, q1 = 0.f;
#pragma unroll
  for (int kc = 0; kc < 8; ++kc) {
    const float* row = qx_part + (((size_t)kc * BB + b) * PP + p) * CC;
    q0 += row[c0];
    q1 += row[c1];
  }
  const float* wrow = w + (size_t)p * CC;
  float t0 = (q0 * inv_sa - wrow[c0]) * rsig;
  float t1 = (q1 * inv_sa - wrow[c1]) * rsig;

  float nr = t0 * t0 + t1 * t1;
#pragma unroll
  for (int off = 32; off; off >>= 1) nr += __shfl_down(nr, off);
  __shared__ float red[4];
  if (lane == 0) red[wave] = nr;
  __syncthreads();
  float norm2 = red[0] + red[1] + red[2] + red[3];
  float scale = 1.f / fmaxf(sqrtf(norm2), 1e-12f);

  float* ob = out_t + (size_t)b * CC * PP + p;
  ob[(size_t)c0 * PP] = t0 * scale;
  ob[(size_t)c1 * PP] = t1 * scale;
}

// ---------------------------------------------------------------------------
extern "C" void kernel_launch(void* const* d_in, const int* in_sizes, int n_in,
                              void* d_out, int out_size, void* d_ws,
                              size_t ws_size, hipStream_t stream) {
  const float* x = (const float*)d_in[0];   // [B,C,H,W]
  const float* w = (const float*)d_in[1];   // [P,C,1,1]
  const float* sf = (const float*)d_in[2];  // [P]

  float* out_t = (float*)d_out;                  // [B,C,P]
  float* assign = out_t + (size_t)BB * CC * PP;  // [B,P,N]

  float* ws = (float*)d_ws;
  float* beta = ws;           // 32
  float* rbeta = ws + 32;     // 32
  float* csq = ws + 64;       // 32
  float* sum_ass = ws + 96;   // 512
  float* qx_part = ws + 608;  // 8 * B * P * C floats (8 MB)

  prep_kernel<<<PP, 64, 0, stream>>>(w, sf, beta, rbeta, csq, sum_ass);
  assign_kernel<<<BB * 32, 256, 0, stream>>>(x, w, rbeta, csq, assign,
                                             sum_ass);
  qx_kernel<<<dim3(32, BB), 256, 0, stream>>>(x, assign, qx_part);
  finalize_kernel<<<BB * PP, 256, 0, stream>>>(qx_part, w, beta, sum_ass,
                                               out_t);
}